// Round 12
// baseline (44.785 us; speedup 1.0000x reference)
//
#include <hip/hip_runtime.h>
#include <math.h>

typedef unsigned short u16;
typedef unsigned int   u32;
typedef unsigned long long u64;

#define Cc   19
#define HWs  16384
#define NPIX 32768
#define FSTR 64               // feature vector: 128 B (8 granules), line-aligned
#define PSTR 24               // prob vector: 48 B (3 granules; 19 real + 5 zero pad)
#define NV   196              // 14x14 halo vectors per 8x8 tile
#define NTILE 512             // 2 * 16 * 16 tiles
#define UNIF19 0x2ABD2ABDu    // f16x2(1/19, 1/19)

typedef _Float16 h2    __attribute__((ext_vector_type(2)));
typedef _Float16 half8 __attribute__((ext_vector_type(8)));
typedef float  floatx4 __attribute__((ext_vector_type(4)));

__device__ inline float fd(u32 a, u32 b, float c) {
  h2 ha = __builtin_bit_cast(h2, a);
  h2 hb = __builtin_bit_cast(h2, b);
#if __has_builtin(__builtin_amdgcn_fdot2)
  return __builtin_amdgcn_fdot2(ha, hb, c, false);
#else
  return c + (float)ha[0] * (float)hb[0] + (float)ha[1] * (float)hb[1];
#endif
}

__device__ inline u32 pk(float a, float b) {
  h2 h; h[0] = (_Float16)a; h[1] = (_Float16)b;
  return __builtin_bit_cast(u32, h);
}

// ---------- PRE: feat normalize+transpose (blocks 0..1023) | softmax (1024..1151) ----------
__global__ __launch_bounds__(256) void pre_kernel(
    const float* __restrict__ logits,
    const float* __restrict__ xsrc, const float* __restrict__ xema,
    u16* __restrict__ osrc, u16* __restrict__ oema, u16* __restrict__ pt) {
  __shared__ float smem[5376];
  int bid = blockIdx.x;
  int t = threadIdx.x;

  if (bid < 1024) {
    float* tile = smem;                 // 64*65
    float* part = smem + 4160;          // 256
    float* invn = smem + 4416;          // 64
    int xb = bid & 255, b = (bid >> 8) & 1, z = bid >> 9;
    const float* in = z ? xema : xsrc;
    u16* out = z ? oema : osrc;
    int pix0 = xb * 64;
    int w = t >> 6, l = t & 63;

    const float* src = in + (size_t)b * 64 * HWs + pix0;
#pragma unroll
    for (int cc = 0; cc < 16; cc++) {
      int c = cc * 4 + w;
      tile[c * 65 + l] = src[(size_t)c * HWs + l];
    }
    __syncthreads();
    float s = 0.f;
#pragma unroll
    for (int c = w * 16; c < w * 16 + 16; c++) { float a = tile[c * 65 + l]; s += a * a; }
    part[w * 64 + l] = s;
    __syncthreads();
    if (t < 64) {
      float n = part[t] + part[64 + t] + part[128 + t] + part[192 + t];
      invn[t] = rsqrtf(fmaxf(n, 1e-16f));
    }
    __syncthreads();
    for (int i = t; i < 512; i += 256) {
      int px = i >> 3, q = i & 7;
      float iv = invn[px];
      float v[8];
#pragma unroll
      for (int k = 0; k < 8; k++) v[k] = tile[(q * 8 + k) * 65 + px] * iv;
      uint4 u = make_uint4(pk(v[0], v[1]), pk(v[2], v[3]), pk(v[4], v[5]), pk(v[6], v[7]));
      *((uint4*)(out + (size_t)(b * HWs + pix0 + px) * FSTR) + q) = u;
    }
  } else {
    float* lp = smem;                   // 256*21
    int pb = bid - 1024;
    int gpix = pb * 256 + t;
    int b = gpix >> 14, hw = gpix & (HWs - 1);
    const float* lg = logits + (size_t)b * Cc * HWs + hw;
    float s = 0.f;
    float v[Cc];
#pragma unroll
    for (int c = 0; c < Cc; c++) { v[c] = __expf(lg[(size_t)c * HWs]); s += v[c]; }
    float inv = 1.0f / s;
#pragma unroll
    for (int c = 0; c < Cc; c++) lp[t * 21 + c] = v[c] * inv;
    __syncthreads();
    u16* ob = pt + (size_t)pb * 256 * PSTR;
    for (int i = t; i < 768; i += 256) {
      int px = i / 3, q = i - px * 3;
      float v8[8];
#pragma unroll
      for (int k = 0; k < 8; k++) {
        int c = q * 8 + k;
        v8[k] = (c < Cc) ? lp[px * 21 + c] : 0.f;
      }
      uint4 u = make_uint4(pk(v8[0], v8[1]), pk(v8[2], v8[3]), pk(v8[4], v8[5]), pk(v8[6], v8[7]));
      *((uint4*)(ob + (size_t)px * PSTR) + q) = u;
    }
  }
}

// ---------- ST: MFMA banded Gram, two-phase staging, fused atomic finish ----------
__global__ __launch_bounds__(512, 4) void st_kernel(
    const u16* __restrict__ fsrc, const u16* __restrict__ fema,
    const u16* __restrict__ pt, const int* __restrict__ gt,
    const float* __restrict__ mix, float* __restrict__ acc) {
  __shared__ uint4 fbuf[1568];         // feature halo (fsrc, then fema), XOR-swizzled
  __shared__ uint4 prb[588];           // probs halo (3 granules, stride-3 linear)
  __shared__ float Csc[4][16][113];    // banded Gram scratch (src -> ema)
  __shared__ int   gtt[NV];
  __shared__ float mixs[64];
  __shared__ u32   ksh[8][64];
  __shared__ float sacc[8][8];
  __shared__ u32   lastf;

  int bid = blockIdx.x;
  int swz = ((bid & 7) << 6) | (bid >> 3);     // bijective XCD swizzle
  int t = threadIdx.x, wv = t >> 6, lane = t & 63;
  int b  = swz >> 8;
  int th = (swz >> 4) & 15, tw = swz & 15;
  int h0 = th << 3, w0 = tw << 3;

  int nr = lane / 7, nc = lane - nr * 7;       // neighbor offsets (lane < 49)
  bool lact = lane < 49;

  // ---- phase 1 staging: fsrc halo + probs + gt + mix ----
  const uint4* FS = (const uint4*)fsrc;
  const uint4* FE = (const uint4*)fema;
  for (int i = t; i < 1568; i += 512) {
    int vec = i >> 3, q = i & 7;
    int r = vec / 14, c = vec - r * 14;
    int gh = h0 + r - 3, gw = w0 + c - 3;
    uint4 d = make_uint4(0u, 0u, 0u, 0u);
    if (((unsigned)gh < 128u) && ((unsigned)gw < 128u))
      d = FS[((size_t)((b << 14) | (gh << 7) | gw) << 3) + q];
    fbuf[(vec << 3) | (q ^ (vec & 7))] = d;
  }
  const uint4* PT3 = (const uint4*)pt;
  for (int i = t; i < 588; i += 512) {
    int vec = i / 3, q = i - vec * 3;
    int r = vec / 14, c = vec - r * 14;
    int gh = h0 + r - 3, gw = w0 + c - 3;
    uint4 d = make_uint4(UNIF19, UNIF19, UNIF19, UNIF19);   // OOB: uniform 1/19 probs
    if (((unsigned)gh < 128u) && ((unsigned)gw < 128u))
      d = PT3[(size_t)((b << 14) | (gh << 7) | gw) * 3 + q];
    prb[vec * 3 + q] = d;
  }
  for (int i = t; i < NV; i += 512) {
    int r = i / 14, c = i - r * 14;
    int gh = h0 + r - 3, gw = w0 + c - 3;
    int g = 0;
    if (((unsigned)gh < 128u) && ((unsigned)gw < 128u))
      g = gt[(b << 14) | (gh << 7) | gw];
    gtt[i] = g;
  }
  if (t < 64) {
    int r = t >> 3, c = t & 7;
    mixs[t] = mix[(b << 14) | ((h0 + r) << 7) | (w0 + c)];
  }
  __syncthreads();

  // ---- gram geometry: wave wv -> row-tile rt = wv>>1, col-half hf = wv&1 ----
  int rt = wv >> 1, hf = wv & 1;
  int p16 = lane & 15, gq = lane >> 4;
  int va = (2 * rt + (p16 >> 3) + 3) * 14 + ((p16 & 7) + 3);   // A vec = tile pixel p16
  int ntiles = hf ? 3 : 4;
  int cb0 = hf ? 64 : 0;                        // col offset within 112-band
  int vb0 = 28 * rt + cb0;                      // halo idx base of first col-tile

  // ---- gram (fsrc) -> Csc ----
  {
    half8 a0 = __builtin_bit_cast(half8, fbuf[(va << 3) | ((gq    ) ^ (va & 7))]);
    half8 a1 = __builtin_bit_cast(half8, fbuf[(va << 3) | ((gq + 4) ^ (va & 7))]);
    for (int ct = 0; ct < ntiles; ct++) {
      int vb = vb0 + ct * 16 + p16;
      half8 b0 = __builtin_bit_cast(half8, fbuf[(vb << 3) | ((gq    ) ^ (vb & 7))]);
      half8 b1 = __builtin_bit_cast(half8, fbuf[(vb << 3) | ((gq + 4) ^ (vb & 7))]);
      floatx4 a4 = {0.f, 0.f, 0.f, 0.f};
      a4 = __builtin_amdgcn_mfma_f32_16x16x32_f16(a0, b0, a4, 0, 0, 0);
      a4 = __builtin_amdgcn_mfma_f32_16x16x32_f16(a1, b1, a4, 0, 0, 0);
      int row = gq << 2, col = cb0 + ct * 16 + p16;
#pragma unroll
      for (int r = 0; r < 4; r++) Csc[rt][row + r][col] = a4[r];  // C: col=lane&15, row=(lane>>4)*4+r
    }
  }
  __syncthreads();                              // gram done: fbuf free, Csc valid

  float psum = 0, ssum = 0, posa = 0, nega = 0, pcntW = 0, vcntW = 0, cntW = 0;
  int ri = wv & 1;                              // row within row-tile

  // ---- phase 2 staging (fema into fbuf) — overlaps epilogue A below ----
  for (int i = t; i < 1568; i += 512) {
    int vec = i >> 3, q = i & 7;
    int r = vec / 14, c = vec - r * 14;
    int gh = h0 + r - 3, gw = w0 + c - 3;
    uint4 d = make_uint4(0u, 0u, 0u, 0u);
    if (((unsigned)gh < 128u) && ((unsigned)gw < 128u))
      d = FE[((size_t)((b << 14) | (gh << 7) | gw) << 3) + q];
    fbuf[(vec << 3) | (q ^ (vec & 7))] = d;
  }

  // ---- epilogue A: source sums (wave wv owns spatial row wv); reads Csc/gtt only ----
  for (int tc = 0; tc < 8; ++tc) {
    int vcH = (wv + 3) * 14 + (tc + 3);
    int gtcv = gtt[vcH];
    if (gtcv != 255) {
      int cbi = lact ? ((ri + nr) * 14 + (tc + nc)) : 0;
      float sims = Csc[rt][ri * 8 + tc][cbi];   // OOB neighbors: zero vectors -> 0
      int vnH = lact ? ((wv + nr) * 14 + (tc + nc)) : vcH;
      int gtn = gtt[vnH];                       // OOB: staged 0 (ref zero-pad)
      bool pos = (gtn == gtcv);
      if (lact) { ssum += sims; if (pos) psum += sims; }
      u64 mk = __ballot(lact && pos);
      pcntW += (float)__popcll(mk);
      vcntW += 1.f;
    }
  }
  __syncthreads();                              // fema staged; epilogue A done with Csc

  // ---- gram (fema) -> Csc ----
  {
    half8 a0 = __builtin_bit_cast(half8, fbuf[(va << 3) | ((gq    ) ^ (va & 7))]);
    half8 a1 = __builtin_bit_cast(half8, fbuf[(va << 3) | ((gq + 4) ^ (va & 7))]);
    for (int ct = 0; ct < ntiles; ct++) {
      int vb = vb0 + ct * 16 + p16;
      half8 b0 = __builtin_bit_cast(half8, fbuf[(vb << 3) | ((gq    ) ^ (vb & 7))]);
      half8 b1 = __builtin_bit_cast(half8, fbuf[(vb << 3) | ((gq + 4) ^ (vb & 7))]);
      floatx4 a4 = {0.f, 0.f, 0.f, 0.f};
      a4 = __builtin_amdgcn_mfma_f32_16x16x32_f16(a0, b0, a4, 0, 0, 0);
      a4 = __builtin_amdgcn_mfma_f32_16x16x32_f16(a1, b1, a4, 0, 0, 0);
      int row = gq << 2, col = cb0 + ct * 16 + p16;
#pragma unroll
      for (int r = 0; r < 4; r++) Csc[rt][row + r][col] = a4[r];
    }
  }
  __syncthreads();

  // ---- epilogue B: target top-k ----
  for (int tc = 0; tc < 8; ++tc) {
    if (mixs[(wv << 3) | tc] < 0.5f) {          // wave-uniform
      int vcH = (wv + 3) * 14 + (tc + 3);
      int vnH = lact ? ((wv + nr) * 14 + (tc + nc)) : vcH;
      int cbi = lact ? ((ri + nr) * 14 + (tc + nc)) : 0;
      float v = lact ? Csc[rt][ri * 8 + tc][cbi] : 0.f;

      uint4 pA = prb[vnH * 3 + 0], pB = prb[vnH * 3 + 1], pC = prb[vnH * 3 + 2];
      uint4 qA = prb[vcH * 3 + 0], qB = prb[vcH * 3 + 1], qC = prb[vcH * 3 + 2];
      float p0 = 0, p1 = 0, p2 = 0;
      p0 = fd(qA.x,pA.x,p0); p0 = fd(qA.y,pA.y,p0); p0 = fd(qA.z,pA.z,p0); p0 = fd(qA.w,pA.w,p0);
      p1 = fd(qB.x,pB.x,p1); p1 = fd(qB.y,pB.y,p1); p1 = fd(qB.z,pB.z,p1); p1 = fd(qB.w,pB.w,p1);
      p2 = fd(qC.x,pC.x,p2); p2 = fd(qC.y,pC.y,p2); p2 = fd(qC.z,pC.z,p2); p2 = fd(qC.w,pC.w,p2);
      float cp = (p0 + p1) + p2;                // OOB: staged 1/19 pattern -> 1/19

      // u32 sortable key: top-26 monotone float bits | lane (distinct)
      u32 bits = __float_as_uint(v);
      u32 mono = (bits & 0x80000000u) ? ~bits : (bits | 0x80000000u);
      u32 key = (mono & 0xFFFFFFC0u) | (u32)lane;
      ksh[wv][lane] = key;
      int rd = 0;
      const uint4* kr = (const uint4*)ksh[wv];
#pragma unroll
      for (int j = 0; j < 12; j++) {
        uint4 qq = kr[j];
        rd += (qq.x > key); rd += (qq.y > key); rd += (qq.z > key); rd += (qq.w > key);
      }
      rd += (ksh[wv][48] > key);
      if (lact) {
        if (rd < 9)   posa += v * cp;                     // top-9 most similar
        if (rd >= 41) nega += (1.f - v) * (1.f - cp);     // bottom-8 of 49
      }
      cntW += 1.f;
    }
  }

  // ---- block reduce ----
#pragma unroll
  for (int off = 32; off; off >>= 1) {
    psum += __shfl_xor(psum, off); ssum += __shfl_xor(ssum, off);
    posa += __shfl_xor(posa, off); nega += __shfl_xor(nega, off);
  }
  if (lane == 0) {
    sacc[wv][0] = psum;  sacc[wv][1] = pcntW; sacc[wv][2] = ssum;
    sacc[wv][3] = posa;  sacc[wv][4] = nega;  sacc[wv][5] = vcntW;
    sacc[wv][6] = cntW;  sacc[wv][7] = 0.f;
  }
  __syncthreads();
  // ---- agent-scope atomic accumulate (no threadfence) ----
  if (t < 7) {
    float s = 0.f;
#pragma unroll
    for (int k = 0; k < 8; k++) s += sacc[k][t];
    __hip_atomic_fetch_add(&acc[t], s, __ATOMIC_RELAXED, __HIP_MEMORY_SCOPE_AGENT);
  }
  __syncthreads();   // drains vmcnt: the 7 adds are globally performed past here
  if (t == 0) {
    u32* tick = (u32*)&acc[7];
    u32 old = __hip_atomic_fetch_add(tick, 1u, __ATOMIC_ACQ_REL, __HIP_MEMORY_SCOPE_AGENT);
    lastf = (old == (u32)(NTILE - 1));
  }
  __syncthreads();
  if (lastf && t == 0) {
    float a[7];
#pragma unroll
    for (int c = 0; c < 7; c++)
      a[c] = __hip_atomic_load(&acc[c], __ATOMIC_RELAXED, __HIP_MEMORY_SCOPE_AGENT);
    float psumT = a[0], pcntT = a[1], ssumT = a[2];
    float posaT = a[3], negaT = a[4], vcntT = a[5], cntT = a[6];
    float nsumT = ssumT - psumT;
    float ncntT = 49.f * vcntT - pcntT;
    float* outp = acc + 8;                      // out pointer stashed after acc
    float* out = (float*)__builtin_bit_cast(void*, *(unsigned long long*)outp);
    out[0] = -(psumT / fmaxf(pcntT, 1.0f));
    out[1] =  (nsumT / fmaxf(ncntT, 1.0f));
    out[2] = -(posaT / fmaxf(9.0f * cntT, 1.0f));
    out[3] = -(negaT / fmaxf(8.0f * cntT, 1.0f));
  }
}

// tiny helper to stash the out pointer into ws (graph-capture-safe, deterministic)
__global__ void put_ptr_kernel(float* acc, float* out) {
  if (threadIdx.x == 0) *(unsigned long long*)(acc + 8) = __builtin_bit_cast(unsigned long long, out);
}

extern "C" void kernel_launch(void* const* d_in, const int* in_sizes, int n_in,
                              void* d_out, int out_size, void* d_ws, size_t ws_size,
                              hipStream_t stream) {
  const float* logits = (const float*)d_in[0];
  const int*   gt     = (const int*)  d_in[1];
  const float* xema   = (const float*)d_in[2];
  const float* xsrc   = (const float*)d_in[3];
  const float* mix    = (const float*)d_in[4];
  float* out = (float*)d_out;

  float* acc  = (float*)d_ws;                                     // 7 sums + ticket + out-ptr
  u16* fsrc = (u16*)((char*)d_ws + 64);                           // NPIX*FSTR f16 = 4 MB
  u16* fema = fsrc + (size_t)NPIX * FSTR;                         // 4 MB
  u16* pt   = fema + (size_t)NPIX * FSTR;                         // NPIX*PSTR f16 = 1.5 MB

  hipMemsetAsync(acc, 0, 32, stream);                             // zero acc[0..6] + ticket
  put_ptr_kernel<<<1, 64, 0, stream>>>(acc, out);
  pre_kernel<<<1152, 256, 0, stream>>>(logits, xsrc, xema, fsrc, fema, pt);
  st_kernel<<<NTILE, 512, 0, stream>>>(fsrc, fema, pt, gt, mix, acc);
}

// Round 13
// 30.316 us; speedup vs baseline: 1.4773x; 1.4773x over previous
//
#include <hip/hip_runtime.h>
#include <math.h>

typedef unsigned short u16;
typedef unsigned int   u32;
typedef unsigned long long u64;

#define Cc   19
#define HWs  16384
#define NPIX 32768
#define FSTR 64               // feature vector: 128 B (8 granules), line-aligned
#define PSTR 24               // prob vector: 48 B (3 granules; 19 real + 5 zero pad)
#define NV   196              // 14x14 halo vectors per 8x8 tile
#define NTILE 512             // 2 * 16 * 16 tiles
#define UNIF19 0x2ABD2ABDu    // f16x2(1/19, 1/19)

typedef _Float16 h2    __attribute__((ext_vector_type(2)));
typedef _Float16 half8 __attribute__((ext_vector_type(8)));
typedef float  floatx4 __attribute__((ext_vector_type(4)));

__device__ inline float fd(u32 a, u32 b, float c) {
  h2 ha = __builtin_bit_cast(h2, a);
  h2 hb = __builtin_bit_cast(h2, b);
#if __has_builtin(__builtin_amdgcn_fdot2)
  return __builtin_amdgcn_fdot2(ha, hb, c, false);
#else
  return c + (float)ha[0] * (float)hb[0] + (float)ha[1] * (float)hb[1];
#endif
}

__device__ inline u32 pk(float a, float b) {
  h2 h; h[0] = (_Float16)a; h[1] = (_Float16)b;
  return __builtin_bit_cast(u32, h);
}

// ---------- PRE: feat normalize+transpose (blocks 0..1023) | softmax (1024..1151) ----------
__global__ __launch_bounds__(256) void pre_kernel(
    const float* __restrict__ logits,
    const float* __restrict__ xsrc, const float* __restrict__ xema,
    u16* __restrict__ osrc, u16* __restrict__ oema, u16* __restrict__ pt) {
  __shared__ float smem[5376];
  int bid = blockIdx.x;
  int t = threadIdx.x;

  if (bid < 1024) {
    float* tile = smem;                 // 64*65
    float* part = smem + 4160;          // 256
    float* invn = smem + 4416;          // 64
    int xb = bid & 255, b = (bid >> 8) & 1, z = bid >> 9;
    const float* in = z ? xema : xsrc;
    u16* out = z ? oema : osrc;
    int pix0 = xb * 64;
    int w = t >> 6, l = t & 63;

    const float* src = in + (size_t)b * 64 * HWs + pix0;
#pragma unroll
    for (int cc = 0; cc < 16; cc++) {
      int c = cc * 4 + w;
      tile[c * 65 + l] = src[(size_t)c * HWs + l];
    }
    __syncthreads();
    float s = 0.f;
#pragma unroll
    for (int c = w * 16; c < w * 16 + 16; c++) { float a = tile[c * 65 + l]; s += a * a; }
    part[w * 64 + l] = s;
    __syncthreads();
    if (t < 64) {
      float n = part[t] + part[64 + t] + part[128 + t] + part[192 + t];
      invn[t] = rsqrtf(fmaxf(n, 1e-16f));
    }
    __syncthreads();
    for (int i = t; i < 512; i += 256) {
      int px = i >> 3, q = i & 7;
      float iv = invn[px];
      float v[8];
#pragma unroll
      for (int k = 0; k < 8; k++) v[k] = tile[(q * 8 + k) * 65 + px] * iv;
      uint4 u = make_uint4(pk(v[0], v[1]), pk(v[2], v[3]), pk(v[4], v[5]), pk(v[6], v[7]));
      *((uint4*)(out + (size_t)(b * HWs + pix0 + px) * FSTR) + q) = u;
    }
  } else {
    float* lp = smem;                   // 256*21
    int pb = bid - 1024;
    int gpix = pb * 256 + t;
    int b = gpix >> 14, hw = gpix & (HWs - 1);
    const float* lg = logits + (size_t)b * Cc * HWs + hw;
    float s = 0.f;
    float v[Cc];
#pragma unroll
    for (int c = 0; c < Cc; c++) { v[c] = __expf(lg[(size_t)c * HWs]); s += v[c]; }
    float inv = 1.0f / s;
#pragma unroll
    for (int c = 0; c < Cc; c++) lp[t * 21 + c] = v[c] * inv;
    __syncthreads();
    u16* ob = pt + (size_t)pb * 256 * PSTR;
    for (int i = t; i < 768; i += 256) {
      int px = i / 3, q = i - px * 3;
      float v8[8];
#pragma unroll
      for (int k = 0; k < 8; k++) {
        int c = q * 8 + k;
        v8[k] = (c < Cc) ? lp[px * 21 + c] : 0.f;
      }
      uint4 u = make_uint4(pk(v8[0], v8[1]), pk(v8[2], v8[3]), pk(v8[4], v8[5]), pk(v8[6], v8[7]));
      *((uint4*)(ob + (size_t)px * PSTR) + q) = u;
    }
  }
}

// ---------- ST: MFMA banded Gram (f16 scratch), single-phase staging ----------
// Gram band per row-tile t (16 px = spatial rows 2t,2t+1): halo cols 28t .. 28t+112.
// Fragment pattern (verified): lane l reads granule (l>>4) of vector (l&15); C: col=lane&15,row=(lane>>4)*4+r.
__global__ __launch_bounds__(512, 4) void st_kernel(
    const u16* __restrict__ fsrc, const u16* __restrict__ fema,
    const u16* __restrict__ pt, const int* __restrict__ gt,
    const float* __restrict__ mix, float* __restrict__ partials) {
  __shared__ uint4 fsb[1568];          // fsrc halo, XOR-swizzled granules (25088 B)
  __shared__ uint4 feb[1568];          // fema halo (25088 B)
  __shared__ uint4 prb[588];           // probs halo (9408 B)
  __shared__ _Float16 Csc[4][16][113]; // banded Gram scratch, f16 (14464 B)
  __shared__ int   gtt[NV];
  __shared__ float mixs[64];
  __shared__ u32   ksh[8][64];
  __shared__ float sacc[8][8];
  // total ~77.4 KB -> 2 blocks/CU

  int bid = blockIdx.x;
  int swz = ((bid & 7) << 6) | (bid >> 3);     // bijective XCD swizzle
  int t = threadIdx.x, wv = t >> 6, lane = t & 63;
  int b  = swz >> 8;
  int th = (swz >> 4) & 15, tw = swz & 15;
  int h0 = th << 3, w0 = tw << 3;

  int nr = lane / 7, nc = lane - nr * 7;       // neighbor offsets (lane < 49)
  bool lact = lane < 49;

  // ---- staging: fsrc + fema halos (swizzled), probs, gt, mix — all up front ----
  const uint4* FS = (const uint4*)fsrc;
  const uint4* FE = (const uint4*)fema;
  for (int i = t; i < 3136; i += 512) {
    int ii = (i >= 1568) ? (i - 1568) : i;
    int vec = ii >> 3, q = ii & 7;
    int r = vec / 14, c = vec - r * 14;
    int gh = h0 + r - 3, gw = w0 + c - 3;
    uint4 d = make_uint4(0u, 0u, 0u, 0u);
    if (((unsigned)gh < 128u) && ((unsigned)gw < 128u)) {
      size_t gidx = ((size_t)((b << 14) | (gh << 7) | gw) << 3) + q;
      d = (i >= 1568) ? FE[gidx] : FS[gidx];
    }
    (i >= 1568 ? feb : fsb)[(vec << 3) | (q ^ (vec & 7))] = d;
  }
  const uint4* PT3 = (const uint4*)pt;
  for (int i = t; i < 588; i += 512) {
    int vec = i / 3, q = i - vec * 3;
    int r = vec / 14, c = vec - r * 14;
    int gh = h0 + r - 3, gw = w0 + c - 3;
    uint4 d = make_uint4(UNIF19, UNIF19, UNIF19, UNIF19);   // OOB: uniform 1/19 probs
    if (((unsigned)gh < 128u) && ((unsigned)gw < 128u))
      d = PT3[(size_t)((b << 14) | (gh << 7) | gw) * 3 + q];
    prb[vec * 3 + q] = d;
  }
  for (int i = t; i < NV; i += 512) {
    int r = i / 14, c = i - r * 14;
    int gh = h0 + r - 3, gw = w0 + c - 3;
    int g = 0;
    if (((unsigned)gh < 128u) && ((unsigned)gw < 128u))
      g = gt[(b << 14) | (gh << 7) | gw];
    gtt[i] = g;
  }
  if (t < 64) {
    int r = t >> 3, c = t & 7;
    mixs[t] = mix[(b << 14) | ((h0 + r) << 7) | (w0 + c)];
  }
  __syncthreads();

  // ---- gram geometry: wave wv -> row-tile rt = wv>>1, col-half hf = wv&1 ----
  int rt = wv >> 1, hf = wv & 1;
  int p16 = lane & 15, gq = lane >> 4;
  int va = (2 * rt + (p16 >> 3) + 3) * 14 + ((p16 & 7) + 3);   // A vec = tile pixel p16
  int ntiles = hf ? 3 : 4;
  int cb0 = hf ? 64 : 0;                        // col offset within 112-band
  int vb0 = 28 * rt + cb0;                      // halo idx base of first col-tile

  // ---- gram (fsrc) -> Csc (f16) ----
  {
    half8 a0 = __builtin_bit_cast(half8, fsb[(va << 3) | ((gq    ) ^ (va & 7))]);
    half8 a1 = __builtin_bit_cast(half8, fsb[(va << 3) | ((gq + 4) ^ (va & 7))]);
    for (int ct = 0; ct < ntiles; ct++) {
      int vb = vb0 + ct * 16 + p16;
      half8 b0 = __builtin_bit_cast(half8, fsb[(vb << 3) | ((gq    ) ^ (vb & 7))]);
      half8 b1 = __builtin_bit_cast(half8, fsb[(vb << 3) | ((gq + 4) ^ (vb & 7))]);
      floatx4 a4 = {0.f, 0.f, 0.f, 0.f};
      a4 = __builtin_amdgcn_mfma_f32_16x16x32_f16(a0, b0, a4, 0, 0, 0);
      a4 = __builtin_amdgcn_mfma_f32_16x16x32_f16(a1, b1, a4, 0, 0, 0);
      int row = gq << 2, col = cb0 + ct * 16 + p16;
#pragma unroll
      for (int r = 0; r < 4; r++) Csc[rt][row + r][col] = (_Float16)a4[r];
    }
  }
  __syncthreads();

  float psum = 0, ssum = 0, posa = 0, nega = 0, pcntW = 0, vcntW = 0, cntW = 0;
  int ri = wv & 1;                              // row within row-tile

  // ---- epilogue A: source sums (wave wv owns spatial row wv) ----
  for (int tc = 0; tc < 8; ++tc) {
    int vcH = (wv + 3) * 14 + (tc + 3);
    int gtcv = gtt[vcH];
    if (gtcv != 255) {
      int cbi = lact ? ((ri + nr) * 14 + (tc + nc)) : 0;
      float sims = (float)Csc[rt][ri * 8 + tc][cbi];   // OOB neighbors: zero vectors -> 0
      int vnH = lact ? ((wv + nr) * 14 + (tc + nc)) : vcH;
      int gtn = gtt[vnH];                       // OOB: staged 0 (ref zero-pad)
      bool pos = (gtn == gtcv);
      if (lact) { ssum += sims; if (pos) psum += sims; }
      u64 mk = __ballot(lact && pos);
      pcntW += (float)__popcll(mk);
      vcntW += 1.f;
    }
  }
  __syncthreads();                              // before Csc reuse

  // ---- gram (fema) -> Csc ----
  {
    half8 a0 = __builtin_bit_cast(half8, feb[(va << 3) | ((gq    ) ^ (va & 7))]);
    half8 a1 = __builtin_bit_cast(half8, feb[(va << 3) | ((gq + 4) ^ (va & 7))]);
    for (int ct = 0; ct < ntiles; ct++) {
      int vb = vb0 + ct * 16 + p16;
      half8 b0 = __builtin_bit_cast(half8, feb[(vb << 3) | ((gq    ) ^ (vb & 7))]);
      half8 b1 = __builtin_bit_cast(half8, feb[(vb << 3) | ((gq + 4) ^ (vb & 7))]);
      floatx4 a4 = {0.f, 0.f, 0.f, 0.f};
      a4 = __builtin_amdgcn_mfma_f32_16x16x32_f16(a0, b0, a4, 0, 0, 0);
      a4 = __builtin_amdgcn_mfma_f32_16x16x32_f16(a1, b1, a4, 0, 0, 0);
      int row = gq << 2, col = cb0 + ct * 16 + p16;
#pragma unroll
      for (int r = 0; r < 4; r++) Csc[rt][row + r][col] = (_Float16)a4[r];
    }
  }
  __syncthreads();

  // ---- epilogue B: target top-k ----
  for (int tc = 0; tc < 8; ++tc) {
    if (mixs[(wv << 3) | tc] < 0.5f) {          // wave-uniform
      int vcH = (wv + 3) * 14 + (tc + 3);
      int vnH = lact ? ((wv + nr) * 14 + (tc + nc)) : vcH;
      int cbi = lact ? ((ri + nr) * 14 + (tc + nc)) : 0;
      float v = lact ? (float)Csc[rt][ri * 8 + tc][cbi] : 0.f;

      uint4 pA = prb[vnH * 3 + 0], pB = prb[vnH * 3 + 1], pC = prb[vnH * 3 + 2];
      uint4 qA = prb[vcH * 3 + 0], qB = prb[vcH * 3 + 1], qC = prb[vcH * 3 + 2];
      float p0 = 0, p1 = 0, p2 = 0;
      p0 = fd(qA.x,pA.x,p0); p0 = fd(qA.y,pA.y,p0); p0 = fd(qA.z,pA.z,p0); p0 = fd(qA.w,pA.w,p0);
      p1 = fd(qB.x,pB.x,p1); p1 = fd(qB.y,pB.y,p1); p1 = fd(qB.z,pB.z,p1); p1 = fd(qB.w,pB.w,p1);
      p2 = fd(qC.x,pC.x,p2); p2 = fd(qC.y,pC.y,p2); p2 = fd(qC.z,pC.z,p2); p2 = fd(qC.w,pC.w,p2);
      float cp = (p0 + p1) + p2;                // OOB: staged 1/19 pattern -> 1/19

      // u32 sortable key: top-26 monotone float bits | lane (distinct)
      u32 bits = __float_as_uint(v);
      u32 mono = (bits & 0x80000000u) ? ~bits : (bits | 0x80000000u);
      u32 key = (mono & 0xFFFFFFC0u) | (u32)lane;
      ksh[wv][lane] = key;
      int rd = 0;
      const uint4* kr = (const uint4*)ksh[wv];
#pragma unroll
      for (int j = 0; j < 12; j++) {
        uint4 qq = kr[j];
        rd += (qq.x > key); rd += (qq.y > key); rd += (qq.z > key); rd += (qq.w > key);
      }
      rd += (ksh[wv][48] > key);
      if (lact) {
        if (rd < 9)   posa += v * cp;                     // top-9 most similar
        if (rd >= 41) nega += (1.f - v) * (1.f - cp);     // bottom-8 of 49
      }
      cntW += 1.f;
    }
  }

  // ---- reduce ----
#pragma unroll
  for (int off = 32; off; off >>= 1) {
    psum += __shfl_xor(psum, off); ssum += __shfl_xor(ssum, off);
    posa += __shfl_xor(posa, off); nega += __shfl_xor(nega, off);
  }
  if (lane == 0) {
    sacc[wv][0] = psum;  sacc[wv][1] = pcntW; sacc[wv][2] = ssum;
    sacc[wv][3] = posa;  sacc[wv][4] = nega;  sacc[wv][5] = vcntW;
    sacc[wv][6] = cntW;  sacc[wv][7] = 0.f;
  }
  __syncthreads();
  if (t < 8) {
    float s = 0.f;
#pragma unroll
    for (int k = 0; k < 8; k++) s += sacc[k][t];
    partials[(size_t)bid * 8 + t] = s;
  }
}

// ---------- F: reduce NTILE partials, combine ----------
__global__ __launch_bounds__(256) void finish_kernel(
    const float* __restrict__ partials, float* __restrict__ out) {
  int t = threadIdx.x, lane = t & 63, wv = t >> 6;
  float s0=0,s1=0,s2=0,s3=0,s4=0,s5=0,s6=0;
  for (int r = t; r < NTILE; r += 256) {
    const float4* p = (const float4*)(partials + (size_t)r * 8);
    float4 x = p[0], y = p[1];
    s0 += x.x; s1 += x.y; s2 += x.z; s3 += x.w;
    s4 += y.x; s5 += y.y; s6 += y.z;
  }
#pragma unroll
  for (int off = 32; off; off >>= 1) {
    s0 += __shfl_xor(s0, off); s1 += __shfl_xor(s1, off);
    s2 += __shfl_xor(s2, off); s3 += __shfl_xor(s3, off);
    s4 += __shfl_xor(s4, off); s5 += __shfl_xor(s5, off);
    s6 += __shfl_xor(s6, off);
  }
  __shared__ float sacc[4][8];
  if (lane == 0) {
    sacc[wv][0]=s0; sacc[wv][1]=s1; sacc[wv][2]=s2; sacc[wv][3]=s3;
    sacc[wv][4]=s4; sacc[wv][5]=s5; sacc[wv][6]=s6;
  }
  __syncthreads();
  if (t == 0) {
    float a[7];
#pragma unroll
    for (int c = 0; c < 7; c++) a[c] = sacc[0][c] + sacc[1][c] + sacc[2][c] + sacc[3][c];
    float psum = a[0], pcnt = a[1], ssum = a[2];
    float posa = a[3], nega = a[4], vcnt = a[5], cnt = a[6];
    float nsum = ssum - psum;
    float ncnt = 49.f * vcnt - pcnt;
    out[0] = -(psum / fmaxf(pcnt, 1.0f));
    out[1] =  (nsum / fmaxf(ncnt, 1.0f));
    out[2] = -(posa / fmaxf(9.0f * cnt, 1.0f));
    out[3] = -(nega / fmaxf(8.0f * cnt, 1.0f));
  }
}

extern "C" void kernel_launch(void* const* d_in, const int* in_sizes, int n_in,
                              void* d_out, int out_size, void* d_ws, size_t ws_size,
                              hipStream_t stream) {
  const float* logits = (const float*)d_in[0];
  const int*   gt     = (const int*)  d_in[1];
  const float* xema   = (const float*)d_in[2];
  const float* xsrc   = (const float*)d_in[3];
  const float* mix    = (const float*)d_in[4];
  float* out = (float*)d_out;

  float* partials = (float*)d_ws;                                 // NTILE*8 f32 = 16 KB
  u16* fsrc = (u16*)((char*)d_ws + NTILE * 8 * sizeof(float));    // NPIX*FSTR f16 = 4 MB
  u16* fema = fsrc + (size_t)NPIX * FSTR;                         // 4 MB
  u16* pt   = fema + (size_t)NPIX * FSTR;                         // NPIX*PSTR f16 = 1.5 MB

  pre_kernel<<<1152, 256, 0, stream>>>(logits, xsrc, xema, fsrc, fema, pt);
  st_kernel<<<NTILE, 512, 0, stream>>>(fsrc, fema, pt, gt, mix, partials);
  finish_kernel<<<1, 256, 0, stream>>>(partials, out);
}

// Round 14
// 30.285 us; speedup vs baseline: 1.4788x; 1.0010x over previous
//
#include <hip/hip_runtime.h>
#include <math.h>

typedef unsigned short u16;
typedef unsigned int   u32;
typedef unsigned long long u64;

#define Cc   19
#define HWs  16384
#define NPIX 32768
#define FSTR 64               // feature vector: 128 B (8 granules), line-aligned
#define PSTR 24               // prob vector: 48 B (3 granules; 19 real + 5 zero pad)
#define NV   196              // 14x14 halo vectors per 8x8 tile
#define NTILE 512             // 2 * 16 * 16 tiles
#define UNIF19 0x2ABD2ABDu    // f16x2(1/19, 1/19)

typedef _Float16 h2    __attribute__((ext_vector_type(2)));
typedef _Float16 half8 __attribute__((ext_vector_type(8)));
typedef float  floatx4 __attribute__((ext_vector_type(4)));

__device__ inline float fd(u32 a, u32 b, float c) {
  h2 ha = __builtin_bit_cast(h2, a);
  h2 hb = __builtin_bit_cast(h2, b);
#if __has_builtin(__builtin_amdgcn_fdot2)
  return __builtin_amdgcn_fdot2(ha, hb, c, false);
#else
  return c + (float)ha[0] * (float)hb[0] + (float)ha[1] * (float)hb[1];
#endif
}

__device__ inline u32 pk(float a, float b) {
  h2 h; h[0] = (_Float16)a; h[1] = (_Float16)b;
  return __builtin_bit_cast(u32, h);
}

// ---------- PRE: feat normalize+transpose (blocks 0..1023) | softmax (1024..1151) ----------
__global__ __launch_bounds__(256) void pre_kernel(
    const float* __restrict__ logits,
    const float* __restrict__ xsrc, const float* __restrict__ xema,
    u16* __restrict__ osrc, u16* __restrict__ oema, u16* __restrict__ pt) {
  __shared__ float smem[5376];
  int bid = blockIdx.x;
  int t = threadIdx.x;

  if (bid < 1024) {
    float* tile = smem;                 // 64*65
    float* part = smem + 4160;          // 256
    float* invn = smem + 4416;          // 64
    int xb = bid & 255, b = (bid >> 8) & 1, z = bid >> 9;
    const float* in = z ? xema : xsrc;
    u16* out = z ? oema : osrc;
    int pix0 = xb * 64;
    int w = t >> 6, l = t & 63;

    const float* src = in + (size_t)b * 64 * HWs + pix0;
#pragma unroll
    for (int cc = 0; cc < 16; cc++) {
      int c = cc * 4 + w;
      tile[c * 65 + l] = src[(size_t)c * HWs + l];
    }
    __syncthreads();
    float s = 0.f;
#pragma unroll
    for (int c = w * 16; c < w * 16 + 16; c++) { float a = tile[c * 65 + l]; s += a * a; }
    part[w * 64 + l] = s;
    __syncthreads();
    if (t < 64) {
      float n = part[t] + part[64 + t] + part[128 + t] + part[192 + t];
      invn[t] = rsqrtf(fmaxf(n, 1e-16f));
    }
    __syncthreads();
    for (int i = t; i < 512; i += 256) {
      int px = i >> 3, q = i & 7;
      float iv = invn[px];
      float v[8];
#pragma unroll
      for (int k = 0; k < 8; k++) v[k] = tile[(q * 8 + k) * 65 + px] * iv;
      uint4 u = make_uint4(pk(v[0], v[1]), pk(v[2], v[3]), pk(v[4], v[5]), pk(v[6], v[7]));
      *((uint4*)(out + (size_t)(b * HWs + pix0 + px) * FSTR) + q) = u;
    }
  } else {
    float* lp = smem;                   // 256*21
    int pb = bid - 1024;
    int gpix = pb * 256 + t;
    int b = gpix >> 14, hw = gpix & (HWs - 1);
    const float* lg = logits + (size_t)b * Cc * HWs + hw;
    float s = 0.f;
    float v[Cc];
#pragma unroll
    for (int c = 0; c < Cc; c++) { v[c] = __expf(lg[(size_t)c * HWs]); s += v[c]; }
    float inv = 1.0f / s;
#pragma unroll
    for (int c = 0; c < Cc; c++) lp[t * 21 + c] = v[c] * inv;
    __syncthreads();
    u16* ob = pt + (size_t)pb * 256 * PSTR;
    for (int i = t; i < 768; i += 256) {
      int px = i / 3, q = i - px * 3;
      float v8[8];
#pragma unroll
      for (int k = 0; k < 8; k++) {
        int c = q * 8 + k;
        v8[k] = (c < Cc) ? lp[px * 21 + c] : 0.f;
      }
      uint4 u = make_uint4(pk(v8[0], v8[1]), pk(v8[2], v8[3]), pk(v8[4], v8[5]), pk(v8[6], v8[7]));
      *((uint4*)(ob + (size_t)px * PSTR) + q) = u;
    }
  }
}

// ---------- ST: MFMA banded Gram (f16 scratch), T14 reg-staged fema ----------
// LDS ~52.3 KB -> 3 blocks/CU; fema halo staged global->reg early, reg->LDS after src-Gram.
__global__ __launch_bounds__(512, 6) void st_kernel(
    const u16* __restrict__ fsrc, const u16* __restrict__ fema,
    const u16* __restrict__ pt, const int* __restrict__ gt,
    const float* __restrict__ mix, float* __restrict__ partials) {
  __shared__ uint4 fsb[1568];          // feature halo: fsrc, then fema (25088 B)
  __shared__ uint4 prb[588];           // probs halo (9408 B)
  __shared__ _Float16 Csc[4][16][113]; // banded Gram scratch, f16 (14464 B)
  __shared__ int   gtt[NV];
  __shared__ float mixs[64];
  __shared__ u32   ksh[8][64];
  __shared__ float sacc[8][8];

  int bid = blockIdx.x;
  int swz = ((bid & 7) << 6) | (bid >> 3);     // bijective XCD swizzle
  int t = threadIdx.x, wv = t >> 6, lane = t & 63;
  int b  = swz >> 8;
  int th = (swz >> 4) & 15, tw = swz & 15;
  int h0 = th << 3, w0 = tw << 3;

  int nr = lane / 7, nc = lane - nr * 7;       // neighbor offsets (lane < 49)
  bool lact = lane < 49;

  const uint4* FS = (const uint4*)fsrc;
  const uint4* FE = (const uint4*)fema;

  // ---- T14 step 1: issue fema halo loads into registers (latency hides under all below) ----
  uint4 E[4];
#pragma unroll
  for (int k = 0; k < 4; k++) {
    int i = t + k * 512;
    uint4 d = make_uint4(0u, 0u, 0u, 0u);
    if (i < 1568) {
      int vec = i >> 3, q = i & 7;
      int r = vec / 14, c = vec - r * 14;
      int gh = h0 + r - 3, gw = w0 + c - 3;
      if (((unsigned)gh < 128u) && ((unsigned)gw < 128u))
        d = FE[((size_t)((b << 14) | (gh << 7) | gw) << 3) + q];
    }
    E[k] = d;
  }

  // ---- staging: fsrc halo (swizzled), probs, gt, mix ----
  for (int i = t; i < 1568; i += 512) {
    int vec = i >> 3, q = i & 7;
    int r = vec / 14, c = vec - r * 14;
    int gh = h0 + r - 3, gw = w0 + c - 3;
    uint4 d = make_uint4(0u, 0u, 0u, 0u);
    if (((unsigned)gh < 128u) && ((unsigned)gw < 128u))
      d = FS[((size_t)((b << 14) | (gh << 7) | gw) << 3) + q];
    fsb[(vec << 3) | (q ^ (vec & 7))] = d;
  }
  const uint4* PT3 = (const uint4*)pt;
  for (int i = t; i < 588; i += 512) {
    int vec = i / 3, q = i - vec * 3;
    int r = vec / 14, c = vec - r * 14;
    int gh = h0 + r - 3, gw = w0 + c - 3;
    uint4 d = make_uint4(UNIF19, UNIF19, UNIF19, UNIF19);   // OOB: uniform 1/19 probs
    if (((unsigned)gh < 128u) && ((unsigned)gw < 128u))
      d = PT3[(size_t)((b << 14) | (gh << 7) | gw) * 3 + q];
    prb[vec * 3 + q] = d;
  }
  for (int i = t; i < NV; i += 512) {
    int r = i / 14, c = i - r * 14;
    int gh = h0 + r - 3, gw = w0 + c - 3;
    int g = 0;
    if (((unsigned)gh < 128u) && ((unsigned)gw < 128u))
      g = gt[(b << 14) | (gh << 7) | gw];
    gtt[i] = g;
  }
  if (t < 64) {
    int r = t >> 3, c = t & 7;
    mixs[t] = mix[(b << 14) | ((h0 + r) << 7) | (w0 + c)];
  }
  __syncthreads();

  // ---- gram geometry: wave wv -> row-tile rt = wv>>1, col-half hf = wv&1 ----
  int rt = wv >> 1, hf = wv & 1;
  int p16 = lane & 15, gq = lane >> 4;
  int va = (2 * rt + (p16 >> 3) + 3) * 14 + ((p16 & 7) + 3);   // A vec = tile pixel p16
  int ntiles = hf ? 3 : 4;
  int cb0 = hf ? 64 : 0;                        // col offset within 112-band
  int vb0 = 28 * rt + cb0;                      // halo idx base of first col-tile

  // ---- gram (fsrc) -> Csc (f16) ----
  {
    half8 a0 = __builtin_bit_cast(half8, fsb[(va << 3) | ((gq    ) ^ (va & 7))]);
    half8 a1 = __builtin_bit_cast(half8, fsb[(va << 3) | ((gq + 4) ^ (va & 7))]);
    for (int ct = 0; ct < ntiles; ct++) {
      int vb = vb0 + ct * 16 + p16;
      half8 b0 = __builtin_bit_cast(half8, fsb[(vb << 3) | ((gq    ) ^ (vb & 7))]);
      half8 b1 = __builtin_bit_cast(half8, fsb[(vb << 3) | ((gq + 4) ^ (vb & 7))]);
      floatx4 a4 = {0.f, 0.f, 0.f, 0.f};
      a4 = __builtin_amdgcn_mfma_f32_16x16x32_f16(a0, b0, a4, 0, 0, 0);
      a4 = __builtin_amdgcn_mfma_f32_16x16x32_f16(a1, b1, a4, 0, 0, 0);
      int row = gq << 2, col = cb0 + ct * 16 + p16;
#pragma unroll
      for (int r = 0; r < 4; r++) Csc[rt][row + r][col] = (_Float16)a4[r];
    }
  }
  __syncthreads();                              // src-gram done: fsb dead, Csc valid

  // ---- T14 step 2: write fema regs -> fsb (overlaps epilogue A) ----
#pragma unroll
  for (int k = 0; k < 4; k++) {
    int i = t + k * 512;
    if (i < 1568) {
      int vec = i >> 3, q = i & 7;
      fsb[(vec << 3) | (q ^ (vec & 7))] = E[k];
    }
  }

  float psum = 0, ssum = 0, posa = 0, nega = 0, pcntW = 0, vcntW = 0, cntW = 0;
  int ri = wv & 1;                              // row within row-tile

  // ---- epilogue A: source sums (reads Csc/gtt only; independent of fsb writes) ----
  for (int tc = 0; tc < 8; ++tc) {
    int vcH = (wv + 3) * 14 + (tc + 3);
    int gtcv = gtt[vcH];
    if (gtcv != 255) {
      int cbi = lact ? ((ri + nr) * 14 + (tc + nc)) : 0;
      float sims = (float)Csc[rt][ri * 8 + tc][cbi];   // OOB neighbors: zero vectors -> 0
      int vnH = lact ? ((wv + nr) * 14 + (tc + nc)) : vcH;
      int gtn = gtt[vnH];                       // OOB: staged 0 (ref zero-pad)
      bool pos = (gtn == gtcv);
      if (lact) { ssum += sims; if (pos) psum += sims; }
      u64 mk = __ballot(lact && pos);
      pcntW += (float)__popcll(mk);
      vcntW += 1.f;
    }
  }
  __syncthreads();                              // fema in fsb; epilogue A done with Csc

  // ---- gram (fema) -> Csc ----
  {
    half8 a0 = __builtin_bit_cast(half8, fsb[(va << 3) | ((gq    ) ^ (va & 7))]);
    half8 a1 = __builtin_bit_cast(half8, fsb[(va << 3) | ((gq + 4) ^ (va & 7))]);
    for (int ct = 0; ct < ntiles; ct++) {
      int vb = vb0 + ct * 16 + p16;
      half8 b0 = __builtin_bit_cast(half8, fsb[(vb << 3) | ((gq    ) ^ (vb & 7))]);
      half8 b1 = __builtin_bit_cast(half8, fsb[(vb << 3) | ((gq + 4) ^ (vb & 7))]);
      floatx4 a4 = {0.f, 0.f, 0.f, 0.f};
      a4 = __builtin_amdgcn_mfma_f32_16x16x32_f16(a0, b0, a4, 0, 0, 0);
      a4 = __builtin_amdgcn_mfma_f32_16x16x32_f16(a1, b1, a4, 0, 0, 0);
      int row = gq << 2, col = cb0 + ct * 16 + p16;
#pragma unroll
      for (int r = 0; r < 4; r++) Csc[rt][row + r][col] = (_Float16)a4[r];
    }
  }
  __syncthreads();

  // ---- epilogue B: target top-k ----
  for (int tc = 0; tc < 8; ++tc) {
    if (mixs[(wv << 3) | tc] < 0.5f) {          // wave-uniform
      int vcH = (wv + 3) * 14 + (tc + 3);
      int vnH = lact ? ((wv + nr) * 14 + (tc + nc)) : vcH;
      int cbi = lact ? ((ri + nr) * 14 + (tc + nc)) : 0;
      float v = lact ? (float)Csc[rt][ri * 8 + tc][cbi] : 0.f;

      uint4 pA = prb[vnH * 3 + 0], pB = prb[vnH * 3 + 1], pC = prb[vnH * 3 + 2];
      uint4 qA = prb[vcH * 3 + 0], qB = prb[vcH * 3 + 1], qC = prb[vcH * 3 + 2];
      float p0 = 0, p1 = 0, p2 = 0;
      p0 = fd(qA.x,pA.x,p0); p0 = fd(qA.y,pA.y,p0); p0 = fd(qA.z,pA.z,p0); p0 = fd(qA.w,pA.w,p0);
      p1 = fd(qB.x,pB.x,p1); p1 = fd(qB.y,pB.y,p1); p1 = fd(qB.z,pB.z,p1); p1 = fd(qB.w,pB.w,p1);
      p2 = fd(qC.x,pC.x,p2); p2 = fd(qC.y,pC.y,p2); p2 = fd(qC.z,pC.z,p2); p2 = fd(qC.w,pC.w,p2);
      float cp = (p0 + p1) + p2;                // OOB: staged 1/19 pattern -> 1/19

      // u32 sortable key: top-26 monotone float bits | lane (distinct)
      u32 bits = __float_as_uint(v);
      u32 mono = (bits & 0x80000000u) ? ~bits : (bits | 0x80000000u);
      u32 key = (mono & 0xFFFFFFC0u) | (u32)lane;
      ksh[wv][lane] = key;
      int rd = 0;
      const uint4* kr = (const uint4*)ksh[wv];
#pragma unroll
      for (int j = 0; j < 12; j++) {
        uint4 qq = kr[j];
        rd += (qq.x > key); rd += (qq.y > key); rd += (qq.z > key); rd += (qq.w > key);
      }
      rd += (ksh[wv][48] > key);
      if (lact) {
        if (rd < 9)   posa += v * cp;                     // top-9 most similar
        if (rd >= 41) nega += (1.f - v) * (1.f - cp);     // bottom-8 of 49
      }
      cntW += 1.f;
    }
  }

  // ---- reduce ----
#pragma unroll
  for (int off = 32; off; off >>= 1) {
    psum += __shfl_xor(psum, off); ssum += __shfl_xor(ssum, off);
    posa += __shfl_xor(posa, off); nega += __shfl_xor(nega, off);
  }
  if (lane == 0) {
    sacc[wv][0] = psum;  sacc[wv][1] = pcntW; sacc[wv][2] = ssum;
    sacc[wv][3] = posa;  sacc[wv][4] = nega;  sacc[wv][5] = vcntW;
    sacc[wv][6] = cntW;  sacc[wv][7] = 0.f;
  }
  __syncthreads();
  if (t < 8) {
    float s = 0.f;
#pragma unroll
    for (int k = 0; k < 8; k++) s += sacc[k][t];
    partials[(size_t)bid * 8 + t] = s;
  }
}

// ---------- F: reduce NTILE partials, combine ----------
__global__ __launch_bounds__(256) void finish_kernel(
    const float* __restrict__ partials, float* __restrict__ out) {
  int t = threadIdx.x, lane = t & 63, wv = t >> 6;
  float s0=0,s1=0,s2=0,s3=0,s4=0,s5=0,s6=0;
  for (int r = t; r < NTILE; r += 256) {
    const float4* p = (const float4*)(partials + (size_t)r * 8);
    float4 x = p[0], y = p[1];
    s0 += x.x; s1 += x.y; s2 += x.z; s3 += x.w;
    s4 += y.x; s5 += y.y; s6 += y.z;
  }
#pragma unroll
  for (int off = 32; off; off >>= 1) {
    s0 += __shfl_xor(s0, off); s1 += __shfl_xor(s1, off);
    s2 += __shfl_xor(s2, off); s3 += __shfl_xor(s3, off);
    s4 += __shfl_xor(s4, off); s5 += __shfl_xor(s5, off);
    s6 += __shfl_xor(s6, off);
  }
  __shared__ float sacc[4][8];
  if (lane == 0) {
    sacc[wv][0]=s0; sacc[wv][1]=s1; sacc[wv][2]=s2; sacc[wv][3]=s3;
    sacc[wv][4]=s4; sacc[wv][5]=s5; sacc[wv][6]=s6;
  }
  __syncthreads();
  if (t == 0) {
    float a[7];
#pragma unroll
    for (int c = 0; c < 7; c++) a[c] = sacc[0][c] + sacc[1][c] + sacc[2][c] + sacc[3][c];
    float psum = a[0], pcnt = a[1], ssum = a[2];
    float posa = a[3], nega = a[4], vcnt = a[5], cnt = a[6];
    float nsum = ssum - psum;
    float ncnt = 49.f * vcnt - pcnt;
    out[0] = -(psum / fmaxf(pcnt, 1.0f));
    out[1] =  (nsum / fmaxf(ncnt, 1.0f));
    out[2] = -(posa / fmaxf(9.0f * cnt, 1.0f));
    out[3] = -(nega / fmaxf(8.0f * cnt, 1.0f));
  }
}

extern "C" void kernel_launch(void* const* d_in, const int* in_sizes, int n_in,
                              void* d_out, int out_size, void* d_ws, size_t ws_size,
                              hipStream_t stream) {
  const float* logits = (const float*)d_in[0];
  const int*   gt     = (const int*)  d_in[1];
  const float* xema   = (const float*)d_in[2];
  const float* xsrc   = (const float*)d_in[3];
  const float* mix    = (const float*)d_in[4];
  float* out = (float*)d_out;

  float* partials = (float*)d_ws;                                 // NTILE*8 f32 = 16 KB
  u16* fsrc = (u16*)((char*)d_ws + NTILE * 8 * sizeof(float));    // NPIX*FSTR f16 = 4 MB
  u16* fema = fsrc + (size_t)NPIX * FSTR;                         // 4 MB
  u16* pt   = fema + (size_t)NPIX * FSTR;                         // NPIX*PSTR f16 = 1.5 MB

  pre_kernel<<<1152, 256, 0, stream>>>(logits, xsrc, xema, fsrc, fema, pt);
  st_kernel<<<NTILE, 512, 0, stream>>>(fsrc, fema, pt, gt, mix, partials);
  finish_kernel<<<1, 256, 0, stream>>>(partials, out);
}